// Round 17
// baseline (172.666 us; speedup 1.0000x reference)
//
#include <hip/hip_runtime.h>
#include <hip/hip_bf16.h>

#define K1 195
#define K1P 224
#define K2 131
#define K2B 136   // structB padded cols: 272 B rows, 16B-aligned
#define K2P 160
#define OC 256
#define BM 32
#define S1 232   // LDS row stride A1 (bf16): 464 B
#define S2 168   // LDS row stride A2 (bf16): 336 B
#define SO 260   // LDS row stride f32 output tile (1040 B)
#define THREADS 512

typedef __attribute__((ext_vector_type(4))) float f32x4;
typedef __attribute__((ext_vector_type(8))) short bf16x8;
typedef __attribute__((ext_vector_type(4))) short bf16x4;

__device__ __forceinline__ short f2b(float x) {
    __hip_bfloat16 h = __float2bfloat16(x);
    return *reinterpret_cast<short*>(&h);
}
__device__ __forceinline__ float b2f(short x) {
    return __uint_as_float(((unsigned)(unsigned short)x) << 16);
}

// WaP is pre-scaled by 0.25 (exact power-of-2; k2 gather then sums without scaling)
__global__ void prep_weights_v17(const float* __restrict__ Wc, const float* __restrict__ Wa,
                                 __hip_bfloat16* __restrict__ WcP, __hip_bfloat16* __restrict__ WaP) {
    int t = blockIdx.x * blockDim.x + threadIdx.x;
    const int total1 = OC * K1P;
    const int total2 = OC * K2P;
    if (t < total1) {
        int oc = t / K1P, k = t - oc * K1P;
        float v = (k < K1) ? Wc[oc * K1 + k] : 0.0f;
        WcP[t] = __float2bfloat16(v);
    } else if (t < total1 + total2) {
        int u = t - total1;
        int oc = u / K2P, k = u - oc * K2P;
        float v = (k < K2) ? (0.25f * Wa[oc * K2 + k]) : 0.0f;
        WaP[u] = __float2bfloat16(v);
    }
}

// ---- k1: out1 = concat(spatial, structural) x Wc^T + bc, AND free structB export ----
__global__ __launch_bounds__(THREADS) void k1_out1_sb_v17(
        const float* __restrict__ spatial,
        const float* __restrict__ structural,
        const __hip_bfloat16* __restrict__ WcP,
        const float* __restrict__ bc,
        float* __restrict__ out1,
        __hip_bfloat16* __restrict__ structB,
        int n) {
    __shared__ union SMem {
        short A1[BM][S1];
        float ols[BM][SO];   // 33.3 KB
    } smem;

    const int t = threadIdx.x;
    const int r0 = blockIdx.x * BM;

    // zero-pad cols [195,224)
    for (int e = t; e < BM * (K1P - K1); e += THREADS) {
        int r = e / (K1P - K1);
        int k = K1 + (e - r * (K1P - K1));
        smem.A1[r][k] = 0;
    }

    // spatial -> A1[:,0:64] : 16 threads/row, 4 floats/thread
    {
        int r  = t >> 4;
        int c0 = (t & 15) * 4;
        int rr = min(r0 + r, n - 1);
        f32x4 v = *(const f32x4*)(spatial + (size_t)rr * 64 + c0);
        bf16x4 o;
        #pragma unroll
        for (int j = 0; j < 4; ++j) o[j] = f2b(v[j]);
        *(bf16x4*)&smem.A1[r][c0] = o;
    }

    // structural rows r0..r0+31 contiguous: flat float4 streaming -> A1[:,64:195]
    // vectorized LDS store when the 4-elem chunk stays within one row (97%)
    {
        const float* sbase = structural + (size_t)r0 * K2;
        const int nf4 = (BM * K2) / 4;  // 1048
        for (int f = t; f < nf4; f += THREADS) {
            f32x4 v = *(const f32x4*)(sbase + (size_t)f * 4);
            int g = f * 4;
            int r = g / K2;
            int k = g - r * K2;
            if (k <= K2 - 4) {
                bf16x4 o;
                #pragma unroll
                for (int j = 0; j < 4; ++j) o[j] = f2b(v[j]);
                *(bf16x4*)&smem.A1[r][64 + k] = o;   // 8B-aligned iff k even; k parity varies -> 2B elements, 8B store needs 8B align: (64+k)*2 % 8 == 0 iff k%4==0... g=4f => k = 4f - r*131; parity of k not guaranteed. fallback below handles.
            } else {
                #pragma unroll
                for (int j = 0; j < 4; ++j) {
                    int gg = g + j;
                    int rr2 = gg / K2;
                    int kk = gg - rr2 * K2;
                    smem.A1[rr2][64 + kk] = f2b(v[j]);
                }
            }
        }
    }
    __syncthreads();

    // structB export: 17 bf16x8 chunks per row from the staged panel (plain stores)
    for (int u = t; u < BM * 17; u += THREADS) {
        int r = u / 17;
        int c = (u - r * 17) * 8;
        int node = r0 + r;
        if (node < n) {
            bf16x8 v = *(const bf16x8*)&smem.A1[r][64 + c];
            *(bf16x8*)((short*)structB + (size_t)node * K2B + c) = v;
        }
    }

    // GEMM1: swapped operands (A=weights, B=nodes); 8 waves x 32 oc
    const int wid  = t >> 6;
    const int lane = t & 63;
    const int lr   = lane & 15;
    const int lkc  = lane >> 4;
    const int colBase = wid * 32;

    f32x4 acc[2][2];
    #pragma unroll
    for (int i = 0; i < 2; ++i)
        #pragma unroll
        for (int j = 0; j < 2; ++j)
            acc[i][j] = (f32x4){0.f, 0.f, 0.f, 0.f};

    #pragma unroll
    for (int ks = 0; ks < K1P; ks += 32) {
        bf16x8 a[2], b[2];
        #pragma unroll
        for (int rt = 0; rt < 2; ++rt)
            a[rt] = *(const bf16x8*)&smem.A1[rt * 16 + lr][ks + lkc * 8];
        #pragma unroll
        for (int ct = 0; ct < 2; ++ct) {
            int oc = colBase + ct * 16 + lr;
            b[ct] = *(const bf16x8*)(WcP + (size_t)oc * K1P + ks + lkc * 8);
        }
        #pragma unroll
        for (int rt = 0; rt < 2; ++rt)
            #pragma unroll
            for (int ct = 0; ct < 2; ++ct)
                acc[ct][rt] = __builtin_amdgcn_mfma_f32_16x16x32_bf16(b[ct], a[rt], acc[ct][rt], 0, 0, 0);
    }

    __syncthreads();  // A1 reads done; reuse LDS as ols

    #pragma unroll
    for (int ct = 0; ct < 2; ++ct) {
        int oc0 = colBase + ct * 16 + lkc * 4;
        f32x4 b4 = *(const f32x4*)(bc + oc0);
        #pragma unroll
        for (int rt = 0; rt < 2; ++rt)
            *(f32x4*)&smem.ols[rt * 16 + lr][oc0] = acc[ct][rt] + b4;
    }
    __syncthreads();
    #pragma unroll
    for (int i = 0; i < 4; ++i) {
        int row = wid * 4 + i;
        f32x4 v = *(const f32x4*)&smem.ols[row][lane * 4];
        int node = r0 + row;
        if (node < n)
            __builtin_nontemporal_store(v, (f32x4*)(out1 + (size_t)node * OC + lane * 4));
    }
}

// ---- k2: out2 = (self + 3 gathered rows) x (0.25*Wa)^T + ba, bf16 gather ----
__global__ __launch_bounds__(THREADS) void k2_out2_v17(
        const __hip_bfloat16* __restrict__ structB,
        const int* __restrict__ neighbour,
        const __hip_bfloat16* __restrict__ WaP,
        const float* __restrict__ ba,
        float* __restrict__ out2,
        int n) {
    __shared__ union SMem {
        short A2[BM][S2];
        float ols[BM][SO];   // 33.3 KB
    } smem;

    const int t = threadIdx.x;
    const int r0 = blockIdx.x * BM;

    // zero cols [136,160): 96 threads, one 8-chunk each (disjoint from gather region)
    if (t < 96) {
        int r = t / 3;
        int c = K2B + (t - r * 3) * 8;      // 136,144,152
        *(bf16x8*)&smem.A2[r][c] = (bf16x8){0, 0, 0, 0, 0, 0, 0, 0};
    }

    // vectorized gather+SUM (0.25 folded into WaP): 32 rows x 17 chunks of 8 bf16.
    // neighbour ints loaded per-thread (same cache line across the 17 threads
    // sharing a row -> L1 hits); no nidx LDS stage, no extra barrier.
    for (int u = t; u < BM * 17; u += THREADS) {
        int r = u / 17;
        int c = (u - r * 17) * 8;
        int rr = min(r0 + r, n - 1);
        const short* sb = (const short*)structB;
        int n0 = neighbour[(size_t)rr * 3 + 0];
        int n1 = neighbour[(size_t)rr * 3 + 1];
        int n2 = neighbour[(size_t)rr * 3 + 2];
        bf16x8 vs = *(const bf16x8*)(sb + (size_t)rr * K2B + c);
        bf16x8 v0 = *(const bf16x8*)(sb + (size_t)n0 * K2B + c);
        bf16x8 v1 = *(const bf16x8*)(sb + (size_t)n1 * K2B + c);
        bf16x8 v2 = *(const bf16x8*)(sb + (size_t)n2 * K2B + c);
        bf16x8 o;
        #pragma unroll
        for (int j = 0; j < 8; ++j)
            o[j] = f2b(b2f(vs[j]) + b2f(v0[j]) + b2f(v1[j]) + b2f(v2[j]));
        *(bf16x8*)&smem.A2[r][c] = o;
    }
    __syncthreads();

    const int wid  = t >> 6;
    const int lane = t & 63;
    const int lr   = lane & 15;
    const int lkc  = lane >> 4;
    const int colBase = wid * 32;

    f32x4 acc[2][2];
    #pragma unroll
    for (int i = 0; i < 2; ++i)
        #pragma unroll
        for (int j = 0; j < 2; ++j)
            acc[i][j] = (f32x4){0.f, 0.f, 0.f, 0.f};

    #pragma unroll
    for (int ks = 0; ks < K2P; ks += 32) {
        bf16x8 a[2], b[2];
        #pragma unroll
        for (int rt = 0; rt < 2; ++rt)
            a[rt] = *(const bf16x8*)&smem.A2[rt * 16 + lr][ks + lkc * 8];
        #pragma unroll
        for (int ct = 0; ct < 2; ++ct) {
            int oc = colBase + ct * 16 + lr;
            b[ct] = *(const bf16x8*)(WaP + (size_t)oc * K2P + ks + lkc * 8);
        }
        #pragma unroll
        for (int rt = 0; rt < 2; ++rt)
            #pragma unroll
            for (int ct = 0; ct < 2; ++ct)
                acc[ct][rt] = __builtin_amdgcn_mfma_f32_16x16x32_bf16(b[ct], a[rt], acc[ct][rt], 0, 0, 0);
    }

    __syncthreads();  // A2 reads done; reuse LDS as ols

    #pragma unroll
    for (int ct = 0; ct < 2; ++ct) {
        int oc0 = colBase + ct * 16 + lkc * 4;
        f32x4 b4 = *(const f32x4*)(ba + oc0);
        #pragma unroll
        for (int rt = 0; rt < 2; ++rt)
            *(f32x4*)&smem.ols[rt * 16 + lr][oc0] = acc[ct][rt] + b4;
    }
    __syncthreads();
    #pragma unroll
    for (int i = 0; i < 4; ++i) {
        int row = wid * 4 + i;
        f32x4 v = *(const f32x4*)&smem.ols[row][lane * 4];
        int node = r0 + row;
        if (node < n)
            __builtin_nontemporal_store(v, (f32x4*)(out2 + (size_t)node * OC + lane * 4));
    }
}

// ---- fallback: v14-style fused kernel (ws too small for structB) ----
__global__ __launch_bounds__(THREADS) void fused_mesh_v17fb(
        const float* __restrict__ spatial,
        const float* __restrict__ structural,
        const int* __restrict__ neighbour,
        const __hip_bfloat16* __restrict__ WcP,
        const float* __restrict__ bc,
        const __hip_bfloat16* __restrict__ WaP,   // pre-scaled by 0.25
        const float* __restrict__ ba,
        float* __restrict__ out1,
        float* __restrict__ out2,
        int n) {
    __shared__ union SMem {
        struct {
            short A1[BM][S1];
            short A2[BM][S2];
            int   nidx[BM * 3];
        } s;
        float ols[BM][SO];
    } smem;

    const int t = threadIdx.x;
    const int r0 = blockIdx.x * BM;

    if (t < BM * 3) {
        size_t gi = (size_t)r0 * 3 + t;
        smem.s.nidx[t] = (gi < (size_t)n * 3) ? neighbour[gi] : 0;
    }
    for (int e = t; e < BM * (K1P - K1); e += THREADS) {
        int r = e / (K1P - K1);
        int k = K1 + (e - r * (K1P - K1));
        smem.s.A1[r][k] = 0;
    }
    for (int e = t; e < BM * (K2P - K2); e += THREADS) {
        int r = e / (K2P - K2);
        int k = K2 + (e - r * (K2P - K2));
        smem.s.A2[r][k] = 0;
    }
    {
        int r  = t >> 4;
        int c0 = (t & 15) * 4;
        int rr = min(r0 + r, n - 1);
        f32x4 v = *(const f32x4*)(spatial + (size_t)rr * 64 + c0);
        bf16x4 o;
        #pragma unroll
        for (int j = 0; j < 4; ++j) o[j] = f2b(v[j]);
        *(bf16x4*)&smem.s.A1[r][c0] = o;
    }
    __syncthreads();
    for (int e = t; e < BM * K2; e += THREADS) {
        int r = e / K2;
        int k = e - r * K2;
        int rr = min(r0 + r, n - 1);
        float self = structural[(size_t)rr * K2 + k];
        int n0 = smem.s.nidx[r * 3 + 0];
        int n1 = smem.s.nidx[r * 3 + 1];
        int n2 = smem.s.nidx[r * 3 + 2];
        float v = self + structural[(size_t)n0 * K2 + k]
                       + structural[(size_t)n1 * K2 + k]
                       + structural[(size_t)n2 * K2 + k];
        smem.s.A1[r][64 + k] = f2b(self);
        smem.s.A2[r][k]      = f2b(v);     // 0.25 folded into WaP
    }
    __syncthreads();

    const int wid  = t >> 6;
    const int lane = t & 63;
    const int lr   = lane & 15;
    const int lkc  = lane >> 4;
    const int colBase = wid * 32;

    f32x4 acc1[2][2], acc2[2][2];
    #pragma unroll
    for (int i = 0; i < 2; ++i)
        #pragma unroll
        for (int j = 0; j < 2; ++j) {
            acc1[i][j] = (f32x4){0.f, 0.f, 0.f, 0.f};
            acc2[i][j] = (f32x4){0.f, 0.f, 0.f, 0.f};
        }
    #pragma unroll
    for (int ks = 0; ks < K1P; ks += 32) {
        bf16x8 a[2], b[2];
        #pragma unroll
        for (int rt = 0; rt < 2; ++rt)
            a[rt] = *(const bf16x8*)&smem.s.A1[rt * 16 + lr][ks + lkc * 8];
        #pragma unroll
        for (int ct = 0; ct < 2; ++ct) {
            int oc = colBase + ct * 16 + lr;
            b[ct] = *(const bf16x8*)(WcP + (size_t)oc * K1P + ks + lkc * 8);
        }
        #pragma unroll
        for (int rt = 0; rt < 2; ++rt)
            #pragma unroll
            for (int ct = 0; ct < 2; ++ct)
                acc1[ct][rt] = __builtin_amdgcn_mfma_f32_16x16x32_bf16(b[ct], a[rt], acc1[ct][rt], 0, 0, 0);
    }
    #pragma unroll
    for (int ks = 0; ks < K2P; ks += 32) {
        bf16x8 a[2], b[2];
        #pragma unroll
        for (int rt = 0; rt < 2; ++rt)
            a[rt] = *(const bf16x8*)&smem.s.A2[rt * 16 + lr][ks + lkc * 8];
        #pragma unroll
        for (int ct = 0; ct < 2; ++ct) {
            int oc = colBase + ct * 16 + lr;
            b[ct] = *(const bf16x8*)(WaP + (size_t)oc * K2P + ks + lkc * 8);
        }
        #pragma unroll
        for (int rt = 0; rt < 2; ++rt)
            #pragma unroll
            for (int ct = 0; ct < 2; ++ct)
                acc2[ct][rt] = __builtin_amdgcn_mfma_f32_16x16x32_bf16(b[ct], a[rt], acc2[ct][rt], 0, 0, 0);
    }
    __syncthreads();
    #pragma unroll
    for (int ct = 0; ct < 2; ++ct) {
        int oc0 = colBase + ct * 16 + lkc * 4;
        f32x4 b4 = *(const f32x4*)(bc + oc0);
        #pragma unroll
        for (int rt = 0; rt < 2; ++rt)
            *(f32x4*)&smem.ols[rt * 16 + lr][oc0] = acc1[ct][rt] + b4;
    }
    __syncthreads();
    #pragma unroll
    for (int i = 0; i < 4; ++i) {
        int row = wid * 4 + i;
        f32x4 v = *(const f32x4*)&smem.ols[row][lane * 4];
        int node = r0 + row;
        if (node < n)
            __builtin_nontemporal_store(v, (f32x4*)(out1 + (size_t)node * OC + lane * 4));
    }
    __syncthreads();
    #pragma unroll
    for (int ct = 0; ct < 2; ++ct) {
        int oc0 = colBase + ct * 16 + lkc * 4;
        f32x4 b4 = *(const f32x4*)(ba + oc0);
        #pragma unroll
        for (int rt = 0; rt < 2; ++rt)
            *(f32x4*)&smem.ols[rt * 16 + lr][oc0] = acc2[ct][rt] + b4;
    }
    __syncthreads();
    #pragma unroll
    for (int i = 0; i < 4; ++i) {
        int row = wid * 4 + i;
        f32x4 v = *(const f32x4*)&smem.ols[row][lane * 4];
        int node = r0 + row;
        if (node < n)
            __builtin_nontemporal_store(v, (f32x4*)(out2 + (size_t)node * OC + lane * 4));
    }
}

extern "C" void kernel_launch(void* const* d_in, const int* in_sizes, int n_in,
                              void* d_out, int out_size, void* d_ws, size_t ws_size,
                              hipStream_t stream) {
    const float* spatial    = (const float*)d_in[0];
    const float* structural = (const float*)d_in[1];
    const int*   neighbour  = (const int*)d_in[2];
    const float* Wc = (const float*)d_in[3];
    const float* bc = (const float*)d_in[4];
    const float* Wa = (const float*)d_in[5];
    const float* ba = (const float*)d_in[6];

    const int n = in_sizes[0] / 64;  // 200000

    float* out1 = (float*)d_out;
    float* out2 = out1 + (size_t)n * OC;

    __hip_bfloat16* WcP = (__hip_bfloat16*)d_ws;
    __hip_bfloat16* WaP = WcP + OC * K1P;

    const size_t wbytes = (size_t)(OC * K1P + OC * K2P) * sizeof(__hip_bfloat16);
    const size_t sbytes = (size_t)n * K2B * sizeof(__hip_bfloat16);
    const bool use_sb = (ws_size >= wbytes + sbytes);
    __hip_bfloat16* structB = (__hip_bfloat16*)((char*)d_ws + wbytes);

    {
        const int total = OC * K1P + OC * K2P;
        prep_weights_v17<<<(total + 255) / 256, 256, 0, stream>>>(Wc, Wa, WcP, WaP);
    }
    const int grid = (n + BM - 1) / BM;  // 6250
    if (use_sb) {
        k1_out1_sb_v17<<<grid, THREADS, 0, stream>>>(spatial, structural, WcP, bc,
                                                     out1, structB, n);
        k2_out2_v17<<<grid, THREADS, 0, stream>>>(structB, neighbour, WaP, ba, out2, n);
    } else {
        fused_mesh_v17fb<<<grid, THREADS, 0, stream>>>(spatial, structural, neighbour,
                                                       WcP, bc, WaP, ba, out1, out2, n);
    }
}

// Round 18
// 166.660 us; speedup vs baseline: 1.0360x; 1.0360x over previous
//
#include <hip/hip_runtime.h>
#include <hip/hip_bf16.h>

#define K1 195
#define K1P 224
#define K2 131
#define K2B 136   // structB padded cols: 272 B rows, 16B-aligned
#define K2P 160
#define OC 256
#define BM 32
#define S1 232   // LDS row stride A1 (bf16): 464 B
#define S2 168   // LDS row stride A2 (bf16): 336 B
#define SO 260   // LDS row stride f32 output tile (1040 B)
#define THREADS 512

typedef __attribute__((ext_vector_type(4))) float f32x4;
typedef __attribute__((ext_vector_type(8))) short bf16x8;
typedef __attribute__((ext_vector_type(4))) short bf16x4;

__device__ __forceinline__ short f2b(float x) {
    __hip_bfloat16 h = __float2bfloat16(x);
    return *reinterpret_cast<short*>(&h);
}
__device__ __forceinline__ float b2f(short x) {
    return __uint_as_float(((unsigned)(unsigned short)x) << 16);
}

__global__ void prep_weights_v18(const float* __restrict__ Wc, const float* __restrict__ Wa,
                                 __hip_bfloat16* __restrict__ WcP, __hip_bfloat16* __restrict__ WaP) {
    int t = blockIdx.x * blockDim.x + threadIdx.x;
    const int total1 = OC * K1P;
    const int total2 = OC * K2P;
    if (t < total1) {
        int oc = t / K1P, k = t - oc * K1P;
        float v = (k < K1) ? Wc[oc * K1 + k] : 0.0f;
        WcP[t] = __float2bfloat16(v);
    } else if (t < total1 + total2) {
        int u = t - total1;
        int oc = u / K2P, k = u - oc * K2P;
        float v = (k < K2) ? Wa[oc * K2 + k] : 0.0f;
        WaP[u] = __float2bfloat16(v);
    }
}

// ---- k1: out1 = concat(spatial, structural) x Wc^T + bc, AND free structB export ----
__global__ __launch_bounds__(THREADS) void k1_out1_sb_v18(
        const float* __restrict__ spatial,
        const float* __restrict__ structural,
        const __hip_bfloat16* __restrict__ WcP,
        const float* __restrict__ bc,
        float* __restrict__ out1,
        __hip_bfloat16* __restrict__ structB,
        int n) {
    __shared__ union SMem {
        short A1[BM][S1];
        float ols[BM][SO];   // 33.3 KB
    } smem;

    const int t = threadIdx.x;
    const int r0 = blockIdx.x * BM;

    // zero-pad cols [195,224)
    for (int e = t; e < BM * (K1P - K1); e += THREADS) {
        int r = e / (K1P - K1);
        int k = K1 + (e - r * (K1P - K1));
        smem.A1[r][k] = 0;
    }

    // spatial -> A1[:,0:64] : 16 threads/row, 4 floats/thread
    {
        int r  = t >> 4;
        int c0 = (t & 15) * 4;
        int rr = min(r0 + r, n - 1);
        f32x4 v = *(const f32x4*)(spatial + (size_t)rr * 64 + c0);
        bf16x4 o;
        #pragma unroll
        for (int j = 0; j < 4; ++j) o[j] = f2b(v[j]);
        *(bf16x4*)&smem.A1[r][c0] = o;
    }

    // structural rows r0..r0+31 contiguous: flat float4 streaming -> A1[:,64:195]
    {
        const float* sbase = structural + (size_t)r0 * K2;
        const int nf4 = (BM * K2) / 4;  // 1048
        for (int f = t; f < nf4; f += THREADS) {
            f32x4 v = *(const f32x4*)(sbase + (size_t)f * 4);
            int g = f * 4;
            #pragma unroll
            for (int j = 0; j < 4; ++j) {
                int gg = g + j;
                int r = gg / K2;
                int k = gg - r * K2;
                smem.A1[r][64 + k] = f2b(v[j]);
            }
        }
    }
    __syncthreads();

    // structB export: 17 bf16x8 chunks per row from the staged panel (plain stores,
    // keeps the 54 MB L2/L3-resident for k2's gather)
    for (int u = t; u < BM * 17; u += THREADS) {
        int r = u / 17;
        int c = (u - r * 17) * 8;
        int node = r0 + r;
        if (node < n) {
            bf16x8 v = *(const bf16x8*)&smem.A1[r][64 + c];
            *(bf16x8*)((short*)structB + (size_t)node * K2B + c) = v;
        }
    }

    // GEMM1: swapped operands (A=weights, B=nodes); 8 waves x 32 oc
    const int wid  = t >> 6;
    const int lane = t & 63;
    const int lr   = lane & 15;
    const int lkc  = lane >> 4;
    const int colBase = wid * 32;

    f32x4 acc[2][2];
    #pragma unroll
    for (int i = 0; i < 2; ++i)
        #pragma unroll
        for (int j = 0; j < 2; ++j)
            acc[i][j] = (f32x4){0.f, 0.f, 0.f, 0.f};

    #pragma unroll
    for (int ks = 0; ks < K1P; ks += 32) {
        bf16x8 a[2], b[2];
        #pragma unroll
        for (int rt = 0; rt < 2; ++rt)
            a[rt] = *(const bf16x8*)&smem.A1[rt * 16 + lr][ks + lkc * 8];
        #pragma unroll
        for (int ct = 0; ct < 2; ++ct) {
            int oc = colBase + ct * 16 + lr;
            b[ct] = *(const bf16x8*)(WcP + (size_t)oc * K1P + ks + lkc * 8);
        }
        #pragma unroll
        for (int rt = 0; rt < 2; ++rt)
            #pragma unroll
            for (int ct = 0; ct < 2; ++ct)
                acc[ct][rt] = __builtin_amdgcn_mfma_f32_16x16x32_bf16(b[ct], a[rt], acc[ct][rt], 0, 0, 0);
    }

    __syncthreads();  // A1 reads done; reuse LDS as ols

    // epilogue: acc -> ols -> 1KB-contiguous NT row stores
    #pragma unroll
    for (int ct = 0; ct < 2; ++ct) {
        int oc0 = colBase + ct * 16 + lkc * 4;
        f32x4 b4 = *(const f32x4*)(bc + oc0);
        #pragma unroll
        for (int rt = 0; rt < 2; ++rt)
            *(f32x4*)&smem.ols[rt * 16 + lr][oc0] = acc[ct][rt] + b4;
    }
    __syncthreads();
    #pragma unroll
    for (int i = 0; i < 4; ++i) {
        int row = wid * 4 + i;
        f32x4 v = *(const f32x4*)&smem.ols[row][lane * 4];
        int node = r0 + row;
        if (node < n)
            __builtin_nontemporal_store(v, (f32x4*)(out1 + (size_t)node * OC + lane * 4));
    }
}

// ---- k2: out2 = 0.25*(self + 3 gathered rows) x Wa^T + ba, bf16 gather ----
__global__ __launch_bounds__(THREADS) void k2_out2_v18(
        const __hip_bfloat16* __restrict__ structB,
        const int* __restrict__ neighbour,
        const __hip_bfloat16* __restrict__ WaP,
        const float* __restrict__ ba,
        float* __restrict__ out2,
        int n) {
    __shared__ union SMem {
        struct {
            short A2[BM][S2];
            int   nidx[BM * 3];
        } s;
        float ols[BM][SO];   // 33.3 KB
    } smem;

    const int t = threadIdx.x;
    const int r0 = blockIdx.x * BM;

    if (t < BM * 3) {
        size_t gi = (size_t)r0 * 3 + t;
        smem.s.nidx[t] = (gi < (size_t)n * 3) ? neighbour[gi] : 0;
    } else if (t < BM * 3 + 96) {
        int e = t - BM * 3;                 // 0..95: zero cols [136,160)
        int r = e / 3;
        int c = K2B + (e - r * 3) * 8;      // 136,144,152
        *(bf16x8*)&smem.s.A2[r][c] = (bf16x8){0, 0, 0, 0, 0, 0, 0, 0};
    }
    __syncthreads();  // nidx ready

    // vectorized gather+average: 32 rows x 17 chunks of 8 bf16 (all 16B-aligned)
    for (int u = t; u < BM * 17; u += THREADS) {
        int r = u / 17;
        int c = (u - r * 17) * 8;
        int rr = min(r0 + r, n - 1);
        const short* sb = (const short*)structB;
        bf16x8 vs = *(const bf16x8*)(sb + (size_t)rr * K2B + c);
        int n0 = smem.s.nidx[r * 3 + 0];
        int n1 = smem.s.nidx[r * 3 + 1];
        int n2 = smem.s.nidx[r * 3 + 2];
        bf16x8 v0 = *(const bf16x8*)(sb + (size_t)n0 * K2B + c);
        bf16x8 v1 = *(const bf16x8*)(sb + (size_t)n1 * K2B + c);
        bf16x8 v2 = *(const bf16x8*)(sb + (size_t)n2 * K2B + c);
        bf16x8 o;
        #pragma unroll
        for (int j = 0; j < 8; ++j)
            o[j] = f2b((b2f(vs[j]) + b2f(v0[j]) + b2f(v1[j]) + b2f(v2[j])) * 0.25f);
        *(bf16x8*)&smem.s.A2[r][c] = o;
    }
    __syncthreads();

    const int wid  = t >> 6;
    const int lane = t & 63;
    const int lr   = lane & 15;
    const int lkc  = lane >> 4;
    const int colBase = wid * 32;

    f32x4 acc[2][2];
    #pragma unroll
    for (int i = 0; i < 2; ++i)
        #pragma unroll
        for (int j = 0; j < 2; ++j)
            acc[i][j] = (f32x4){0.f, 0.f, 0.f, 0.f};

    #pragma unroll
    for (int ks = 0; ks < K2P; ks += 32) {
        bf16x8 a[2], b[2];
        #pragma unroll
        for (int rt = 0; rt < 2; ++rt)
            a[rt] = *(const bf16x8*)&smem.s.A2[rt * 16 + lr][ks + lkc * 8];
        #pragma unroll
        for (int ct = 0; ct < 2; ++ct) {
            int oc = colBase + ct * 16 + lr;
            b[ct] = *(const bf16x8*)(WaP + (size_t)oc * K2P + ks + lkc * 8);
        }
        #pragma unroll
        for (int rt = 0; rt < 2; ++rt)
            #pragma unroll
            for (int ct = 0; ct < 2; ++ct)
                acc[ct][rt] = __builtin_amdgcn_mfma_f32_16x16x32_bf16(b[ct], a[rt], acc[ct][rt], 0, 0, 0);
    }

    __syncthreads();  // A2 reads done; reuse LDS as ols

    #pragma unroll
    for (int ct = 0; ct < 2; ++ct) {
        int oc0 = colBase + ct * 16 + lkc * 4;
        f32x4 b4 = *(const f32x4*)(ba + oc0);
        #pragma unroll
        for (int rt = 0; rt < 2; ++rt)
            *(f32x4*)&smem.ols[rt * 16 + lr][oc0] = acc[ct][rt] + b4;
    }
    __syncthreads();
    #pragma unroll
    for (int i = 0; i < 4; ++i) {
        int row = wid * 4 + i;
        f32x4 v = *(const f32x4*)&smem.ols[row][lane * 4];
        int node = r0 + row;
        if (node < n)
            __builtin_nontemporal_store(v, (f32x4*)(out2 + (size_t)node * OC + lane * 4));
    }
}

// ---- fallback: v14-style fused kernel (used only if ws can't hold structB) ----
__global__ __launch_bounds__(THREADS) void fused_mesh_v18fb(
        const float* __restrict__ spatial,
        const float* __restrict__ structural,
        const int* __restrict__ neighbour,
        const __hip_bfloat16* __restrict__ WcP,
        const float* __restrict__ bc,
        const __hip_bfloat16* __restrict__ WaP,
        const float* __restrict__ ba,
        float* __restrict__ out1,
        float* __restrict__ out2,
        int n) {
    __shared__ union SMem {
        struct {
            short A1[BM][S1];
            short A2[BM][S2];
            int   nidx[BM * 3];
        } s;
        float ols[BM][SO];
    } smem;

    const int t = threadIdx.x;
    const int r0 = blockIdx.x * BM;

    if (t < BM * 3) {
        size_t gi = (size_t)r0 * 3 + t;
        smem.s.nidx[t] = (gi < (size_t)n * 3) ? neighbour[gi] : 0;
    }
    for (int e = t; e < BM * (K1P - K1); e += THREADS) {
        int r = e / (K1P - K1);
        int k = K1 + (e - r * (K1P - K1));
        smem.s.A1[r][k] = 0;
    }
    for (int e = t; e < BM * (K2P - K2); e += THREADS) {
        int r = e / (K2P - K2);
        int k = K2 + (e - r * (K2P - K2));
        smem.s.A2[r][k] = 0;
    }
    {
        int r  = t >> 4;
        int c0 = (t & 15) * 4;
        int rr = min(r0 + r, n - 1);
        f32x4 v = *(const f32x4*)(spatial + (size_t)rr * 64 + c0);
        bf16x4 o;
        #pragma unroll
        for (int j = 0; j < 4; ++j) o[j] = f2b(v[j]);
        *(bf16x4*)&smem.s.A1[r][c0] = o;
    }
    __syncthreads();
    for (int e = t; e < BM * K2; e += THREADS) {
        int r = e / K2;
        int k = e - r * K2;
        int rr = min(r0 + r, n - 1);
        float self = structural[(size_t)rr * K2 + k];
        int n0 = smem.s.nidx[r * 3 + 0];
        int n1 = smem.s.nidx[r * 3 + 1];
        int n2 = smem.s.nidx[r * 3 + 2];
        float v = self + structural[(size_t)n0 * K2 + k]
                       + structural[(size_t)n1 * K2 + k]
                       + structural[(size_t)n2 * K2 + k];
        smem.s.A1[r][64 + k] = f2b(self);
        smem.s.A2[r][k]      = f2b(v * 0.25f);
    }
    __syncthreads();

    const int wid  = t >> 6;
    const int lane = t & 63;
    const int lr   = lane & 15;
    const int lkc  = lane >> 4;
    const int colBase = wid * 32;

    f32x4 acc1[2][2], acc2[2][2];
    #pragma unroll
    for (int i = 0; i < 2; ++i)
        #pragma unroll
        for (int j = 0; j < 2; ++j) {
            acc1[i][j] = (f32x4){0.f, 0.f, 0.f, 0.f};
            acc2[i][j] = (f32x4){0.f, 0.f, 0.f, 0.f};
        }
    #pragma unroll
    for (int ks = 0; ks < K1P; ks += 32) {
        bf16x8 a[2], b[2];
        #pragma unroll
        for (int rt = 0; rt < 2; ++rt)
            a[rt] = *(const bf16x8*)&smem.s.A1[rt * 16 + lr][ks + lkc * 8];
        #pragma unroll
        for (int ct = 0; ct < 2; ++ct) {
            int oc = colBase + ct * 16 + lr;
            b[ct] = *(const bf16x8*)(WcP + (size_t)oc * K1P + ks + lkc * 8);
        }
        #pragma unroll
        for (int rt = 0; rt < 2; ++rt)
            #pragma unroll
            for (int ct = 0; ct < 2; ++ct)
                acc1[ct][rt] = __builtin_amdgcn_mfma_f32_16x16x32_bf16(b[ct], a[rt], acc1[ct][rt], 0, 0, 0);
    }
    #pragma unroll
    for (int ks = 0; ks < K2P; ks += 32) {
        bf16x8 a[2], b[2];
        #pragma unroll
        for (int rt = 0; rt < 2; ++rt)
            a[rt] = *(const bf16x8*)&smem.s.A2[rt * 16 + lr][ks + lkc * 8];
        #pragma unroll
        for (int ct = 0; ct < 2; ++ct) {
            int oc = colBase + ct * 16 + lr;
            b[ct] = *(const bf16x8*)(WaP + (size_t)oc * K2P + ks + lkc * 8);
        }
        #pragma unroll
        for (int rt = 0; rt < 2; ++rt)
            #pragma unroll
            for (int ct = 0; ct < 2; ++ct)
                acc2[ct][rt] = __builtin_amdgcn_mfma_f32_16x16x32_bf16(b[ct], a[rt], acc2[ct][rt], 0, 0, 0);
    }
    __syncthreads();
    #pragma unroll
    for (int ct = 0; ct < 2; ++ct) {
        int oc0 = colBase + ct * 16 + lkc * 4;
        f32x4 b4 = *(const f32x4*)(bc + oc0);
        #pragma unroll
        for (int rt = 0; rt < 2; ++rt)
            *(f32x4*)&smem.ols[rt * 16 + lr][oc0] = acc1[ct][rt] + b4;
    }
    __syncthreads();
    #pragma unroll
    for (int i = 0; i < 4; ++i) {
        int row = wid * 4 + i;
        f32x4 v = *(const f32x4*)&smem.ols[row][lane * 4];
        int node = r0 + row;
        if (node < n)
            __builtin_nontemporal_store(v, (f32x4*)(out1 + (size_t)node * OC + lane * 4));
    }
    __syncthreads();
    #pragma unroll
    for (int ct = 0; ct < 2; ++ct) {
        int oc0 = colBase + ct * 16 + lkc * 4;
        f32x4 b4 = *(const f32x4*)(ba + oc0);
        #pragma unroll
        for (int rt = 0; rt < 2; ++rt)
            *(f32x4*)&smem.ols[rt * 16 + lr][oc0] = acc2[ct][rt] + b4;
    }
    __syncthreads();
    #pragma unroll
    for (int i = 0; i < 4; ++i) {
        int row = wid * 4 + i;
        f32x4 v = *(const f32x4*)&smem.ols[row][lane * 4];
        int node = r0 + row;
        if (node < n)
            __builtin_nontemporal_store(v, (f32x4*)(out2 + (size_t)node * OC + lane * 4));
    }
}

extern "C" void kernel_launch(void* const* d_in, const int* in_sizes, int n_in,
                              void* d_out, int out_size, void* d_ws, size_t ws_size,
                              hipStream_t stream) {
    const float* spatial    = (const float*)d_in[0];
    const float* structural = (const float*)d_in[1];
    const int*   neighbour  = (const int*)d_in[2];
    const float* Wc = (const float*)d_in[3];
    const float* bc = (const float*)d_in[4];
    const float* Wa = (const float*)d_in[5];
    const float* ba = (const float*)d_in[6];

    const int n = in_sizes[0] / 64;  // 200000

    float* out1 = (float*)d_out;
    float* out2 = out1 + (size_t)n * OC;

    __hip_bfloat16* WcP = (__hip_bfloat16*)d_ws;
    __hip_bfloat16* WaP = WcP + OC * K1P;

    const size_t wbytes = (size_t)(OC * K1P + OC * K2P) * sizeof(__hip_bfloat16);
    const size_t sbytes = (size_t)n * K2B * sizeof(__hip_bfloat16);
    const bool use_sb = (ws_size >= wbytes + sbytes);
    __hip_bfloat16* structB = (__hip_bfloat16*)((char*)d_ws + wbytes);

    {
        const int total = OC * K1P + OC * K2P;
        prep_weights_v18<<<(total + 255) / 256, 256, 0, stream>>>(Wc, Wa, WcP, WaP);
    }
    const int grid = (n + BM - 1) / BM;  // 6250
    if (use_sb) {
        k1_out1_sb_v18<<<grid, THREADS, 0, stream>>>(spatial, structural, WcP, bc,
                                                     out1, structB, n);
        k2_out2_v18<<<grid, THREADS, 0, stream>>>(structB, neighbour, WaP, ba, out2, n);
    } else {
        fused_mesh_v18fb<<<grid, THREADS, 0, stream>>>(spatial, structural, neighbour,
                                                       WcP, bc, WaP, ba, out1, out2, n);
    }
}